// Round 19
// baseline (189.017 us; speedup 1.0000x reference)
//
#include <hip/hip_runtime.h>
#include <math.h>

static constexpr int Cdim = 32;   // C
static constexpr int NBES = 8;    // NB
static constexpr int HDIM = 64;   // H
static constexpr int ZDIM = 10;   // Z
static constexpr int TBLN = 8192; // radial table resolution (nearest-neighbor)

typedef _Float16 half8 __attribute__((ext_vector_type(8)));
typedef _Float16 half4 __attribute__((ext_vector_type(4)));
typedef float floatx4 __attribute__((ext_vector_type(4)));

__device__ __forceinline__ float silu_f(float x) {
    return x / (1.0f + __expf(-x));
}

__device__ __forceinline__ float4 shfl4(float4 v, int src) {
    return make_float4(__shfl(v.x, src), __shfl(v.y, src),
                       __shfl(v.z, src), __shfl(v.w, src));
}

// ---------------- node init (EW computed per-block in LDS) ----------------
__global__ __launch_bounds__(256)
void k_node_init(const float* __restrict__ attrs, const float* __restrict__ pos,
                 const float* __restrict__ W_embed, const float* __restrict__ atomE,
                 const float* __restrict__ Wlin0, int* __restrict__ elem,
                 float* __restrict__ energy, int* __restrict__ deg,
                 float4* __restrict__ pos4, _Float16* __restrict__ h16cur,
                 _Float16* __restrict__ h1a16, int N)
{
    __shared__ float sEW[ZDIM * Cdim];
    for (int t = threadIdx.x; t < ZDIM * Cdim; t += 256) {
        int z = t >> 5, d = t & 31;
        float acc = 0.f;
        #pragma unroll
        for (int c = 0; c < Cdim; ++c) acc += W_embed[z * Cdim + c] * Wlin0[c * Cdim + d];
        sEW[t] = acc;
    }
    __syncthreads();
    int n = blockIdx.x * blockDim.x + threadIdx.x;
    if (n >= N) return;
    int e = 0; float best = -1.0f;
    #pragma unroll
    for (int z = 0; z < ZDIM; ++z) {
        float v = attrs[n * ZDIM + z];
        if (v > best) { best = v; e = z; }
    }
    elem[n] = e;
    #pragma unroll
    for (int c = 0; c < Cdim; c += 4) {
        half4 ph, p1;
        #pragma unroll
        for (int q = 0; q < 4; ++q) {
            ph[q] = (_Float16)W_embed[e * Cdim + c + q];
            p1[q] = (_Float16)sEW[e * Cdim + c + q];
        }
        *(half4*)(h16cur + (size_t)n * Cdim + c) = ph;
        *(half4*)(h1a16  + (size_t)n * Cdim + c) = p1;
    }
    energy[n] = atomE[e];
    deg[n] = 0;
    float zf = (float)(e + 1);
    pos4[n] = make_float4(pos[3*n+0], pos[3*n+1], pos[3*n+2],
                          4.0f * zf + powf(zf, 0.23f));
}

// ---------------- filter: mask + degree + packed per-edge data ----------------
__global__ __launch_bounds__(256)
void k_filter(const float4* __restrict__ pos4, const int* __restrict__ snd,
              const int* __restrict__ rcv, unsigned long long* __restrict__ mask,
              int* __restrict__ deg, float4* __restrict__ equadE,
              int2* __restrict__ einfoE, int E)
{
    int e = blockIdx.x * blockDim.x + threadIdx.x;
    int ec = min(e, E - 1);
    int s = snd[ec], t = rcv[ec];
    float4 pt = pos4[t], ps = pos4[s];
    float dx = pt.x - ps.x, dy = pt.y - ps.y, dz = pt.z - ps.z;
    float d2 = dx*dx + dy*dy + dz*dz;
    bool pred = (e < E) && (d2 < 25.0f);
    unsigned long long m = __ballot(pred ? 1 : 0);
    if ((threadIdx.x & 63) == 0) mask[e >> 6] = m;
    if (pred) {
        atomicAdd(&deg[t], 1);
        float r  = sqrtf(d2 + 1e-12f);
        float inv_r = 1.0f / r;
        int i0 = min((int)(r * ((float)TBLN / 5.0f)), TBLN - 1);
        equadE[e] = make_float4(dx * inv_r, dy * inv_r, dz * inv_r,
                                __int_as_float(i0 * 192));
        float tz = floorf(pt.w * 0.25f), tz23 = pt.w - 4.0f * tz;
        float sz = floorf(ps.w * 0.25f), sz23 = ps.w - 4.0f * sz;
        float u  = r * 0.2f;
        float u2 = u*u, u5 = u2*u2*u;
        float fcut = 1.0f - 21.0f*u5 + 35.0f*u5*u - 15.0f*u5*u2;
        float xx = r * (sz23 + tz23) * 2.134471718f;
        float phi = 0.1818f*__expf(-3.2f*xx) + 0.5099f*__expf(-0.9423f*xx)
                  + 0.2802f*__expf(-0.4029f*xx) + 0.02817f*__expf(-0.2016f*xx);
        einfoE[e] = make_int2(s, __float_as_int(tz * sz * inv_r * phi * fcut));
    }
}

// ---------------- scan pass 1 ----------------
__global__ __launch_bounds__(1024)
void k_scan1(const int* __restrict__ deg, int* __restrict__ rowptr,
             int* __restrict__ bsum, int* __restrict__ bhist,
             int* __restrict__ myslot, int N)
{
    __shared__ int wsum[16];
    __shared__ int lhist[64];
    int tid = threadIdx.x, lane = tid & 63, w = tid >> 6;
    if (tid < 64) lhist[tid] = 0;
    __syncthreads();
    int i = blockIdx.x * 1024 + tid;
    int v = (i < N) ? deg[i] : 0;
    if (i < N) myslot[i] = atomicAdd(&lhist[min(v, 63)], 1);
    int s = v;
    #pragma unroll
    for (int d = 1; d < 64; d <<= 1) {
        int u = __shfl_up(s, d);
        if (lane >= d) s += u;
    }
    if (lane == 63) wsum[w] = s;
    __syncthreads();
    if (w == 0 && lane < 16) {
        int x = wsum[lane];
        #pragma unroll
        for (int d = 1; d < 16; d <<= 1) {
            int u = __shfl_up(x, d);
            if (lane >= d) x += u;
        }
        wsum[lane] = x;
    }
    __syncthreads();
    int wave_off = (w == 0) ? 0 : wsum[w - 1];
    if (i < N) rowptr[i] = wave_off + (s - v);
    if (tid == 0) bsum[blockIdx.x] = wsum[15];
    if (tid < 64) bhist[blockIdx.x * 64 + tid] = lhist[tid];
}

// ---------------- scan pass 2 ----------------
__global__ __launch_bounds__(128)
void k_scan2(int* __restrict__ bsum, int nb, int* __restrict__ bhist,
             int* __restrict__ rowptrN)
{
    int tid = threadIdx.x;
    int lane = tid & 63;
    if (tid < 64) {
        int v = (lane < nb) ? bsum[lane] : 0;
        int s = v;
        #pragma unroll
        for (int d = 1; d < 64; d <<= 1) {
            int u = __shfl_up(s, d);
            if (lane >= d) s += u;
        }
        if (lane < nb) bsum[lane] = s - v;
        if (lane == 63) *rowptrN = s;
    } else {
        int b = lane;
        int run = 0;
        for (int blk = 0; blk < nb; ++blk) {
            int t = bhist[blk * 64 + b];
            bhist[blk * 64 + b] = run;
            run += t;
        }
        int s = run;
        #pragma unroll
        for (int d = 1; d < 64; d <<= 1) {
            int u = __shfl_up(s, d);
            if (lane >= d) s += u;
        }
        int excl = s - run;
        for (int blk = 0; blk < nb; ++blk) bhist[blk * 64 + b] += excl;
    }
}

// ---------------- scan pass 3 ----------------
__global__ __launch_bounds__(1024)
void k_scan3(const int* __restrict__ deg, int* __restrict__ rowptr,
             int* __restrict__ cursor, const int* __restrict__ bsum,
             const int* __restrict__ bhist, const int* __restrict__ myslot,
             int* __restrict__ perm, int N)
{
    int i = blockIdx.x * 1024 + threadIdx.x;
    if (i >= N) return;
    int rv = rowptr[i] + bsum[blockIdx.x];
    rowptr[i] = rv;
    cursor[i] = rv;
    int b = min(deg[i], 63);
    perm[bhist[blockIdx.x * 64 + b] + myslot[i]] = i;
}

// ---------------- place: slot copy only ----------------
__global__ __launch_bounds__(256)
void k_place(const int* __restrict__ rcv, const unsigned long long* __restrict__ mask,
             const float4* __restrict__ equadE, const int2* __restrict__ einfoE,
             int* __restrict__ cursor, float4* __restrict__ equad,
             int2* __restrict__ einfo, int E)
{
    int e = blockIdx.x * blockDim.x + threadIdx.x;
    if (e >= E) return;
    if (!((mask[e >> 6] >> (e & 63)) & 1ull)) return;
    int t = rcv[e];
    int slot = atomicAdd(&cursor[t], 1);
    equad[slot] = equadE[e];
    einfo[slot] = einfoE[e];
}

// ---------------- radial tables (both iterations) via f16 MFMA MLP ----------------
__global__ __launch_bounds__(256, 2)
void k_table(const float* __restrict__ Wr0, const float* __restrict__ Wr1,
             const float* __restrict__ Wr2, const float* __restrict__ Wr3,
             _Float16* __restrict__ table)
{
    int tb = blockIdx.x >> 5;
    const float* W0 = Wr0 + tb * NBES * HDIM;
    const float* W1 = Wr1 + tb * HDIM * HDIM;
    const float* W2 = Wr2 + tb * HDIM * HDIM;
    const float* W3 = Wr3 + tb * HDIM * 96;
    _Float16* tbl = table + (size_t)tb * TBLN * 96;

    __shared__ __align__(16) _Float16 sWt0[64*32];
    __shared__ __align__(16) _Float16 sWt1[64*64];
    __shared__ __align__(16) _Float16 sWt2[64*64];
    __shared__ __align__(16) _Float16 sWt3[96*64];
    __shared__ __align__(16) _Float16 sAct[4][64*64];

    for (int idx = threadIdx.x; idx < 64*32; idx += 256) {
        int n = idx >> 5, k = idx & 31;
        float v = (k < NBES) ? W0[k*64 + n] : 0.f;
        *(_Float16*)((char*)sWt0 + n*64 + ((k*2) ^ ((n&3)<<4))) = (_Float16)v;
    }
    for (int idx = threadIdx.x; idx < 64*64; idx += 256) {
        int k = idx >> 6, n = idx & 63;
        int byo = n*128 + ((k*2) ^ ((n&7)<<4));
        *(_Float16*)((char*)sWt1 + byo) = (_Float16)W1[idx];
        *(_Float16*)((char*)sWt2 + byo) = (_Float16)W2[idx];
    }
    for (int idx = threadIdx.x; idx < 64*96; idx += 256) {
        int k = idx / 96, n = idx - k*96;
        *(_Float16*)((char*)sWt3 + n*128 + ((k*2) ^ ((n&7)<<4))) = (_Float16)W3[idx];
    }
    __syncthreads();

    const int wid = threadIdx.x >> 6, lane = threadIdx.x & 63;
    const int l15 = lane & 15, lh = lane >> 4;
    char* actc = (char*)sAct[wid];

    half8 w1f[4], w2f[4][2], w3f[4][2], w4f[6][2];
    #pragma unroll
    for (int nt = 0; nt < 4; ++nt) {
        int nn = nt*16 + l15;
        w1f[nt] = *(half8*)((char*)sWt0 + nn*64 + ((lh*16) ^ ((nn&3)<<4)));
        #pragma unroll
        for (int ks = 0; ks < 2; ++ks) {
            w2f[nt][ks] = *(half8*)((char*)sWt1 + nn*128 + ((ks*64 + lh*16) ^ ((nn&7)<<4)));
            w3f[nt][ks] = *(half8*)((char*)sWt2 + nn*128 + ((ks*64 + lh*16) ^ ((nn&7)<<4)));
        }
    }
    #pragma unroll
    for (int nt = 0; nt < 6; ++nt) {
        int nn = nt*16 + l15;
        #pragma unroll
        for (int ks = 0; ks < 2; ++ks)
            w4f[nt][ks] = *(half8*)((char*)sWt3 + nn*128 + ((ks*64 + lh*16) ^ ((nn&7)<<4)));
    }

    int c0 = ((blockIdx.x & 31)*4 + wid)*64;
    {
        int q = c0 + lane;
        float r = (q + 0.5f) * (5.0f / (float)TBLN);
        float inv_r = 1.0f / r;
        float u  = r * 0.2f;
        float u2 = u*u, u5 = u2*u2*u;
        float fcut = 1.0f - 21.0f*u5 + 35.0f*u5*u - 15.0f*u5*u2;
        float coef = 0.632455532f * inv_r * fcut;
        half8 rv;
        #pragma unroll
        for (int j = 0; j < NBES; ++j)
            rv[j] = (_Float16)(coef * __sinf((float)(j+1) * 0.628318531f * r));
        {
            int sw = (lane & 7) << 4;
            half8 zz = {};
            *(half8*)(actc + lane*128 + ( 0 ^ sw)) = rv;
            *(half8*)(actc + lane*128 + (16 ^ sw)) = zz;
            *(half8*)(actc + lane*128 + (32 ^ sw)) = zz;
            *(half8*)(actc + lane*128 + (48 ^ sw)) = zz;
        }
        __builtin_amdgcn_sched_barrier(0);

        #pragma unroll
        for (int mt = 0; mt < 4; ++mt) {
            int rr = mt*16 + l15;
            int swz = (rr & 7) << 4;
            half8 act = *(half8*)(actc + rr*128 + ((lh*16) ^ swz));
            #pragma unroll
            for (int nt = 0; nt < 4; ++nt) {
                floatx4 z = {0.f,0.f,0.f,0.f};
                floatx4 d = __builtin_amdgcn_mfma_f32_16x16x32_f16(w1f[nt], act, z, 0,0,0);
                half4 pk;
                #pragma unroll
                for (int j = 0; j < 4; ++j) pk[j] = (_Float16)silu_f(d[j]);
                *(half4*)(actc + rr*128 + ((nt*32 + lh*8) ^ swz)) = pk;
            }
        }
        __builtin_amdgcn_sched_barrier(0);

        #pragma unroll
        for (int layer = 0; layer < 2; ++layer) {
            #pragma unroll
            for (int mt = 0; mt < 4; ++mt) {
                int rr = mt*16 + l15;
                int swz = (rr & 7) << 4;
                half8 a0 = *(half8*)(actc + rr*128 + ((      lh*16) ^ swz));
                half8 a1 = *(half8*)(actc + rr*128 + ((64 + lh*16) ^ swz));
                #pragma unroll
                for (int nt = 0; nt < 4; ++nt) {
                    floatx4 z = {0.f,0.f,0.f,0.f};
                    if (layer == 0) {
                        z = __builtin_amdgcn_mfma_f32_16x16x32_f16(w2f[nt][0], a0, z, 0,0,0);
                        z = __builtin_amdgcn_mfma_f32_16x16x32_f16(w2f[nt][1], a1, z, 0,0,0);
                    } else {
                        z = __builtin_amdgcn_mfma_f32_16x16x32_f16(w3f[nt][0], a0, z, 0,0,0);
                        z = __builtin_amdgcn_mfma_f32_16x16x32_f16(w3f[nt][1], a1, z, 0,0,0);
                    }
                    half4 pk;
                    #pragma unroll
                    for (int j = 0; j < 4; ++j) pk[j] = (_Float16)silu_f(z[j]);
                    *(half4*)(actc + rr*128 + ((nt*32 + lh*8) ^ swz)) = pk;
                }
            }
            __builtin_amdgcn_sched_barrier(0);
        }

        #pragma unroll
        for (int mt = 0; mt < 4; ++mt) {
            int rr = mt*16 + l15;
            int swz = (rr & 7) << 4;
            half8 a0 = *(half8*)(actc + rr*128 + ((      lh*16) ^ swz));
            half8 a1 = *(half8*)(actc + rr*128 + ((64 + lh*16) ^ swz));
            int e = c0 + rr;
            #pragma unroll
            for (int nt = 0; nt < 6; ++nt) {
                floatx4 z = {0.f,0.f,0.f,0.f};
                z = __builtin_amdgcn_mfma_f32_16x16x32_f16(w4f[nt][0], a0, z, 0,0,0);
                z = __builtin_amdgcn_mfma_f32_16x16x32_f16(w4f[nt][1], a1, z, 0,0,0);
                half4 pk;
                #pragma unroll
                for (int j = 0; j < 4; ++j) pk[j] = (_Float16)z[j];
                *(half4*)(tbl + (size_t)e*96 + nt*16 + lh*4) = pk;
            }
        }
    }
}

// ---------------- FUSED gather + MFMA epilogue (pipelined edge loads) ----------------
template<int ITER>
__global__ __launch_bounds__(256, 5)
void k_gather_epi(const int* __restrict__ rowptr, const float4* __restrict__ equad,
                  const int2* __restrict__ einfo,
                  const _Float16* __restrict__ h1_16, const _Float16* __restrict__ hcur16,
                  const _Float16* __restrict__ table, const int* __restrict__ perm,
                  float* AO, const int* __restrict__ elem,
                  const float* __restrict__ Wprod, const float* __restrict__ Wsc,
                  const float* __restrict__ Wp, const float* __restrict__ w_ro1,
                  const float* __restrict__ W_m1, const float* __restrict__ w_m2,
                  const float* __restrict__ Wlin_next, _Float16* __restrict__ h1_next16,
                  _Float16* __restrict__ hcur_next16,
                  float* __restrict__ energy, int N)
{
    __shared__ float sWp[1024];
    __shared__ __align__(16) _Float16 sWt16[2048];
    __shared__ float sM1[(ITER == 1) ? 512 : 16];
    __shared__ float sm2[16];
    __shared__ float sro[32];
    __shared__ float sWl[(ITER == 0) ? 1024 : 16];
    __shared__ __align__(16) _Float16 sA16[32 * 296];
    __shared__ int sPerm[32];

    for (int t = threadIdx.x; t < 1024; t += 256) sWp[t] = Wprod[t];
    for (int t = threadIdx.x; t < 2048; t += 256) {
        int l = t >> 10, rem = t & 1023, d = rem >> 5, c = rem & 31;
        *(_Float16*)((char*)sWt16 + l*2048 + d*64 + ((c*2) ^ ((d&3)<<4))) =
            (_Float16)Wprod[(l + 1) * 1024 + c * 32 + d];
    }
    if (ITER == 1)
        for (int t = threadIdx.x; t < 512; t += 256) sM1[t] = W_m1[t];
    if (ITER == 0)
        for (int t = threadIdx.x; t < 1024; t += 256) sWl[t] = Wlin_next[t];
    if (threadIdx.x < 16) sm2[threadIdx.x] = w_m2[threadIdx.x];
    if (threadIdx.x < 32) {
        sro[threadIdx.x] = w_ro1[threadIdx.x];
        int idx = blockIdx.x * 32 + threadIdx.x;
        sPerm[threadIdx.x] = (idx < N) ? perm[idx] : -1;
    }
    __syncthreads();

    int lane = threadIdx.x & 63;
    int gbase = lane & 56;
    int g = threadIdx.x >> 3, j = threadIdx.x & 7, c0 = j * 4;
    int n = sPerm[g];
    bool valid = (n >= 0);

    float acc[9][4];
    #pragma unroll
    for (int m = 0; m < 9; ++m)
        #pragma unroll
        for (int q = 0; q < 4; ++q) acc[m][q] = 0.f;
    float zacc = 0.f;

    if (valid) {
        int lo = rowptr[n], hi = rowptr[n+1];

        if (lo < hi) {
            // prologue: load first pair
            int k0 = lo;
            int k1 = min(lo + 1, hi - 1);
            float4 qd0 = equad[k0];
            float4 qd1 = equad[k1];
            int2 in0 = einfo[k0];
            int2 in1 = einfo[k1];
            bool v1 = (lo + 1 < hi);

            for (int base = lo; base < hi; base += 2) {
                // ---- prefetch next pair (clamped, branch-free) ----
                int nb = base + 2;
                int kn0 = min(nb, hi - 1);
                int kn1 = min(nb + 1, hi - 1);
                float4 qdN0 = equad[kn0];
                float4 qdN1 = equad[kn1];
                int2 inN0 = einfo[kn0];
                int2 inN1 = einfo[kn1];

                // ---- second-level loads for current pair ----
                const char* T00 = (const char*)table + __float_as_int(qd0.w) + c0 * 2;
                const char* T10 = (const char*)table + __float_as_int(qd1.w) + c0 * 2;
                half4 e0a0 = *(const half4*)(T00);
                half4 e0a1 = *(const half4*)(T00 + 64);
                half4 e0a2 = *(const half4*)(T00 + 128);
                half4 e1a0 = *(const half4*)(T10);
                half4 e1a1 = *(const half4*)(T10 + 64);
                half4 e1a2 = *(const half4*)(T10 + 128);

                half4 hv0 = *(const half4*)(h1_16 + (size_t)in0.x * Cdim + c0);
                half4 hv1 = *(const half4*)(h1_16 + (size_t)in1.x * Cdim + c0);

                float vf1 = v1 ? 1.0f : 0.0f;

                if (ITER == 0) {
                    zacc += __int_as_float(in0.y);
                    zacc += vf1 * __int_as_float(in1.y);
                }

                // ---- edge 0 ----
                {
                    float ux = qd0.x, uy = qd0.y, uz = qd0.z;
                    const float s3 = 1.73205081f, s5 = 2.23606798f, s15 = 3.87298335f;
                    float sh1 = s3 * ux, sh2 = s3 * uy, sh3 = s3 * uz;
                    float sh4 = s15 * ux * uy, sh5 = s15 * uy * uz;
                    float sh6 = 0.5f * s5 * (3.0f * uz * uz - 1.0f);
                    float sh7 = s15 * ux * uz;
                    float sh8 = 0.5f * s15 * (ux * ux - uy * uy);

                    #pragma unroll
                    for (int q = 0; q < 4; ++q) {
                        float hb = (float)hv0[q];
                        float m0 = hb * (float)e0a0[q];
                        float m1 = hb * (float)e0a1[q];
                        float m2 = hb * (float)e0a2[q];
                        acc[0][q] += m0;
                        acc[1][q] += sh1 * m1;
                        acc[2][q] += sh2 * m1;
                        acc[3][q] += sh3 * m1;
                        acc[4][q] += sh4 * m2;
                        acc[5][q] += sh5 * m2;
                        acc[6][q] += sh6 * m2;
                        acc[7][q] += sh7 * m2;
                        acc[8][q] += sh8 * m2;
                    }
                }
                // ---- edge 1 (weight vf1) ----
                {
                    float ux = qd1.x, uy = qd1.y, uz = qd1.z;
                    const float s3 = 1.73205081f, s5 = 2.23606798f, s15 = 3.87298335f;
                    float sh1 = s3 * ux, sh2 = s3 * uy, sh3 = s3 * uz;
                    float sh4 = s15 * ux * uy, sh5 = s15 * uy * uz;
                    float sh6 = 0.5f * s5 * (3.0f * uz * uz - 1.0f);
                    float sh7 = s15 * ux * uz;
                    float sh8 = 0.5f * s15 * (ux * ux - uy * uy);

                    #pragma unroll
                    for (int q = 0; q < 4; ++q) {
                        float hb = (float)hv1[q] * vf1;
                        float m0 = hb * (float)e1a0[q];
                        float m1 = hb * (float)e1a1[q];
                        float m2 = hb * (float)e1a2[q];
                        acc[0][q] += m0;
                        acc[1][q] += sh1 * m1;
                        acc[2][q] += sh2 * m1;
                        acc[3][q] += sh3 * m1;
                        acc[4][q] += sh4 * m2;
                        acc[5][q] += sh5 * m2;
                        acc[6][q] += sh6 * m2;
                        acc[7][q] += sh7 * m2;
                        acc[8][q] += sh8 * m2;
                    }
                }

                // rotate pipeline registers
                qd0 = qdN0; qd1 = qdN1; in0 = inN0; in1 = inN1;
                v1 = (nb + 1 < hi);
            }
        }

        #pragma unroll
        for (int m = 1; m <= 8; ++m) {
            half4 pk;
            #pragma unroll
            for (int q = 0; q < 4; ++q) pk[q] = (_Float16)(acc[m][q] * 0.0625f);
            *(half4*)((char*)sA16 + g * 592 + m * 64 + j * 8) = pk;
        }
    }
    __syncthreads();

    // ---- MFMA phase: out[m] = (A_m/16) @ Wprod[L[m]], m=1..8 ----
    {
        int w = threadIdx.x >> 6;
        int l15 = lane & 15, lh = lane >> 4;
        int nhalf = (w >> 1) * 16;
        int mbase = (w & 1) * 4 + 1;
        int node = sPerm[nhalf + l15];
        const int outslot = (ITER == 0) ? 0 : 288;

        half8 af[2][2];
        #pragma unroll
        for (int l = 0; l < 2; ++l)
            #pragma unroll
            for (int nt = 0; nt < 2; ++nt) {
                int row = nt * 16 + l15;
                af[l][nt] = *(half8*)((char*)sWt16 + l*2048 + row*64 +
                                      ((lh*16) ^ ((row&3)<<4)));
            }
        #pragma unroll
        for (int mi = 0; mi < 4; ++mi) {
            int m = mbase + mi;
            int l = (m <= 3) ? 0 : 1;
            half8 bf = *(half8*)((char*)sA16 + (nhalf + l15) * 592 + m * 64 + lh * 16);
            #pragma unroll
            for (int nt = 0; nt < 2; ++nt) {
                floatx4 z = {0.f, 0.f, 0.f, 0.f};
                z = __builtin_amdgcn_mfma_f32_16x16x32_f16(af[l][nt], bf, z, 0, 0, 0);
                if (node >= 0)
                    *(floatx4*)(AO + (size_t)node * 576 + outslot + m * 32 +
                                nt * 16 + lh * 4) = z;
            }
        }
    }

    // ---- hs / scalar channel ----
    if (valid) {
        int el = elem[n];
        half4 hq4 = *(const half4*)(hcur16 + (size_t)n * Cdim + c0);
        float4 hown = make_float4((float)hq4[0], (float)hq4[1],
                                  (float)hq4[2], (float)hq4[3]);
        float4 A0own = make_float4(acc[0][0]*0.0625f, acc[0][1]*0.0625f,
                                   acc[0][2]*0.0625f, acc[0][3]*0.0625f);
        const float* Ws = Wsc + (size_t)el * 1024;
        float hs[4] = {0.f, 0.f, 0.f, 0.f};

        #pragma unroll
        for (int j2 = 0; j2 < 8; ++j2) {
            int src = gbase + j2;
            float4 a4 = shfl4(A0own, src);
            float4 h4 = shfl4(hown, src);
            float aq[4] = {a4.x, a4.y, a4.z, a4.w};
            float hq[4] = {h4.x, h4.y, h4.z, h4.w};
            #pragma unroll
            for (int q = 0; q < 4; ++q) {
                int c = j2 * 4 + q;
                float4 wp = *(const float4*)&sWp[c * 32 + c0];
                float4 wv = *(const float4*)(Ws + c * 32 + c0);
                hs[0] += aq[q] * wp.x + hq[q] * wv.x;
                hs[1] += aq[q] * wp.y + hq[q] * wv.y;
                hs[2] += aq[q] * wp.z + hq[q] * wv.z;
                hs[3] += aq[q] * wp.w + hq[q] * wv.w;
            }
        }
        {
            const float* wpb = Wp + el * 32;
            float4 p1 = *(const float4*)(wpb + c0);
            float4 p2 = *(const float4*)(wpb + 320 + c0);
            float4 p3 = *(const float4*)(wpb + 640 + c0);
            float p1a[4] = {p1.x, p1.y, p1.z, p1.w};
            float p2a[4] = {p2.x, p2.y, p2.z, p2.w};
            float p3a[4] = {p3.x, p3.y, p3.z, p3.w};
            #pragma unroll
            for (int d = 0; d < 4; ++d) {
                float A = acc[0][d] * 0.0625f, A2 = A * A;
                hs[d] += p1a[d] * A + p2a[d] * A2 + p3a[d] * (A2 * A);
            }
        }

        float eadd;
        if (ITER == 0) {
            float a = hs[0]*sro[c0] + hs[1]*sro[c0+1] + hs[2]*sro[c0+2] + hs[3]*sro[c0+3];
            a += __shfl_xor(a, 1); a += __shfl_xor(a, 2); a += __shfl_xor(a, 4);
            eadd = a + 7.1998f * zacc;
        } else {
            float tj[16];
            #pragma unroll
            for (int q = 0; q < 16; ++q) {
                float tv = 0.f;
                #pragma unroll
                for (int d = 0; d < 4; ++d) tv += hs[d] * sM1[(c0 + d) * 16 + q];
                tv += __shfl_xor(tv, 1); tv += __shfl_xor(tv, 2); tv += __shfl_xor(tv, 4);
                tj[q] = tv;
            }
            float a = 0.f;
            #pragma unroll
            for (int q = 0; q < 16; ++q) a += silu_f(tj[q]) * sm2[q];
            eadd = a;
        }
        if (j == 0) energy[n] += eadd;

        const int outslot = (ITER == 0) ? 0 : 288;
        *(float4*)(AO + (size_t)n * 576 + outslot + c0) = make_float4(hs[0], hs[1], hs[2], hs[3]);

        if (ITER == 0) {
            half4 ph;
            #pragma unroll
            for (int q = 0; q < 4; ++q) ph[q] = (_Float16)hs[q];
            *(half4*)(hcur_next16 + (size_t)n * Cdim + c0) = ph;

            float4 hsv = make_float4(hs[0], hs[1], hs[2], hs[3]);
            float o[4] = {0.f, 0.f, 0.f, 0.f};
            #pragma unroll
            for (int j2 = 0; j2 < 8; ++j2) {
                float4 h4 = shfl4(hsv, gbase + j2);
                float hq[4] = {h4.x, h4.y, h4.z, h4.w};
                #pragma unroll
                for (int q = 0; q < 4; ++q) {
                    float4 wv = *(const float4*)&sWl[(j2 * 4 + q) * 32 + c0];
                    o[0] += hq[q] * wv.x; o[1] += hq[q] * wv.y;
                    o[2] += hq[q] * wv.z; o[3] += hq[q] * wv.w;
                }
            }
            half4 p1;
            #pragma unroll
            for (int q = 0; q < 4; ++q) p1[q] = (_Float16)o[q];
            *(half4*)(h1_next16 + (size_t)n * Cdim + c0) = p1;
        }
    }
}

extern "C" void kernel_launch(void* const* d_in, const int* in_sizes, int n_in,
                              void* d_out, int out_size, void* d_ws, size_t ws_size,
                              hipStream_t stream)
{
    const float* attrs   = (const float*)d_in[0];
    const float* pos     = (const float*)d_in[1];
    const int*   snd     = (const int*)d_in[2];
    const int*   rcv     = (const int*)d_in[3];
    const float* W_embed = (const float*)d_in[4];
    const float* atomE   = (const float*)d_in[5];
    const float* Wr0     = (const float*)d_in[6];
    const float* Wr1     = (const float*)d_in[7];
    const float* Wr2     = (const float*)d_in[8];
    const float* Wr3     = (const float*)d_in[9];
    const float* Wlin    = (const float*)d_in[10];
    const float* Wsc     = (const float*)d_in[11];
    const float* Wprod   = (const float*)d_in[12];
    const float* Wp      = (const float*)d_in[13];
    const float* w_ro1   = (const float*)d_in[14];
    const float* W_m1    = (const float*)d_in[15];
    const float* w_m2    = (const float*)d_in[16];

    const int N = in_sizes[1] / 3;
    const int E = in_sizes[2];

    float* energy = (float*)d_out;
    float* feats  = (float*)d_out + N;

    char* ws = (char*)d_ws;
    size_t off = 0;
    auto alloc = [&](size_t bytes) { void* p = ws + off; off = (off + bytes + 255) & ~(size_t)255; return p; };
    int*  deg    = (int*)alloc((size_t)N * 4);
    int*  cursor = (int*)alloc((size_t)N * 4);
    int*  rowptr = (int*)alloc((size_t)(N + 1) * 4);
    unsigned long long* mask = (unsigned long long*)alloc((size_t)((E + 63) / 64) * 8);
    float4* equad  = (float4*)alloc((size_t)E * 16);
    int2*   einfo  = (int2*)alloc((size_t)E * 8);
    float4* equadE = (float4*)alloc((size_t)E * 16);
    int2*   einfoE = (int2*)alloc((size_t)E * 8);
    int*  elem   = (int*)alloc((size_t)N * 4);
    float4* pos4 = (float4*)alloc((size_t)N * 16);
    _Float16* h16cur = (_Float16*)alloc((size_t)N * Cdim * 2);
    _Float16* h16b   = (_Float16*)alloc((size_t)N * Cdim * 2);
    _Float16* h1a16  = (_Float16*)alloc((size_t)N * Cdim * 2);
    _Float16* h1b16  = (_Float16*)alloc((size_t)N * Cdim * 2);
    _Float16* table = (_Float16*)alloc((size_t)2 * TBLN * 96 * 2);
    int* bsum   = (int*)alloc(64 * 4);
    int* bhist  = (int*)alloc(64 * 64 * 4);
    int* myslot = (int*)alloc((size_t)N * 4);
    int* perm   = (int*)alloc((size_t)N * 4);

    const int NB1024 = (N + 1023) / 1024;

    k_node_init<<<(N + 255)/256, 256, 0, stream>>>(attrs, pos, W_embed, atomE, Wlin, elem,
                                                   energy, deg, pos4, h16cur, h1a16, N);
    k_filter<<<(E + 255)/256, 256, 0, stream>>>(pos4, snd, rcv, mask, deg, equadE, einfoE, E);
    k_scan1<<<NB1024, 1024, 0, stream>>>(deg, rowptr, bsum, bhist, myslot, N);
    k_scan2<<<1, 128, 0, stream>>>(bsum, NB1024, bhist, rowptr + N);
    k_scan3<<<NB1024, 1024, 0, stream>>>(deg, rowptr, cursor, bsum, bhist, myslot, perm, N);
    k_place<<<(E + 255)/256, 256, 0, stream>>>(rcv, mask, equadE, einfoE, cursor,
                                               equad, einfo, E);
    k_table<<<64, 256, 0, stream>>>(Wr0, Wr1, Wr2, Wr3, table);

    const int NBLK = (N + 31) / 32;

    // ---- iteration 0 ----
    k_gather_epi<0><<<NBLK, 256, 0, stream>>>(rowptr, equad, einfo, h1a16, h16cur, table,
        perm, feats, elem, Wprod, Wsc, Wp, w_ro1, W_m1, w_m2,
        Wlin + 1024, h1b16, h16b, energy, N);

    // ---- iteration 1 ----
    k_gather_epi<1><<<NBLK, 256, 0, stream>>>(rowptr, equad, einfo, h1b16, h16b,
        table + (size_t)TBLN * 96,
        perm, feats, elem, Wprod + 3072, Wsc + 10240, Wp + 960, w_ro1, W_m1, w_m2,
        Wlin, h1b16, h16b, energy, N);
}

// Round 20
// 183.257 us; speedup vs baseline: 1.0314x; 1.0314x over previous
//
#include <hip/hip_runtime.h>
#include <math.h>

static constexpr int Cdim = 32;   // C
static constexpr int NBES = 8;    // NB
static constexpr int HDIM = 64;   // H
static constexpr int ZDIM = 10;   // Z
static constexpr int TBLN = 8192; // radial table resolution (nearest-neighbor)

typedef _Float16 half8 __attribute__((ext_vector_type(8)));
typedef _Float16 half4 __attribute__((ext_vector_type(4)));
typedef float floatx4 __attribute__((ext_vector_type(4)));

__device__ __forceinline__ float silu_f(float x) {
    return x / (1.0f + __expf(-x));
}

__device__ __forceinline__ float4 shfl4(float4 v, int src) {
    return make_float4(__shfl(v.x, src), __shfl(v.y, src),
                       __shfl(v.z, src), __shfl(v.w, src));
}

// ---------------- node init (EW computed per-block in LDS) ----------------
__global__ __launch_bounds__(256)
void k_node_init(const float* __restrict__ attrs, const float* __restrict__ pos,
                 const float* __restrict__ W_embed, const float* __restrict__ atomE,
                 const float* __restrict__ Wlin0, int* __restrict__ elem,
                 float* __restrict__ energy, int* __restrict__ deg,
                 float4* __restrict__ pos4, _Float16* __restrict__ h16cur,
                 _Float16* __restrict__ h1a16, int N)
{
    __shared__ float sEW[ZDIM * Cdim];
    for (int t = threadIdx.x; t < ZDIM * Cdim; t += 256) {
        int z = t >> 5, d = t & 31;
        float acc = 0.f;
        #pragma unroll
        for (int c = 0; c < Cdim; ++c) acc += W_embed[z * Cdim + c] * Wlin0[c * Cdim + d];
        sEW[t] = acc;
    }
    __syncthreads();
    int n = blockIdx.x * blockDim.x + threadIdx.x;
    if (n >= N) return;
    int e = 0; float best = -1.0f;
    #pragma unroll
    for (int z = 0; z < ZDIM; ++z) {
        float v = attrs[n * ZDIM + z];
        if (v > best) { best = v; e = z; }
    }
    elem[n] = e;
    #pragma unroll
    for (int c = 0; c < Cdim; c += 4) {
        half4 ph, p1;
        #pragma unroll
        for (int q = 0; q < 4; ++q) {
            ph[q] = (_Float16)W_embed[e * Cdim + c + q];
            p1[q] = (_Float16)sEW[e * Cdim + c + q];
        }
        *(half4*)(h16cur + (size_t)n * Cdim + c) = ph;
        *(half4*)(h1a16  + (size_t)n * Cdim + c) = p1;
    }
    energy[n] = atomE[e];
    deg[n] = 0;
    float zf = (float)(e + 1);
    pos4[n] = make_float4(pos[3*n+0], pos[3*n+1], pos[3*n+2],
                          4.0f * zf + powf(zf, 0.23f));
}

// ---------------- filter: mask + degree + packed per-edge data ----------------
__global__ __launch_bounds__(256)
void k_filter(const float4* __restrict__ pos4, const int* __restrict__ snd,
              const int* __restrict__ rcv, unsigned long long* __restrict__ mask,
              int* __restrict__ deg, float4* __restrict__ equadE,
              int2* __restrict__ einfoE, int E)
{
    int e = blockIdx.x * blockDim.x + threadIdx.x;
    int ec = min(e, E - 1);
    int s = snd[ec], t = rcv[ec];
    float4 pt = pos4[t], ps = pos4[s];
    float dx = pt.x - ps.x, dy = pt.y - ps.y, dz = pt.z - ps.z;
    float d2 = dx*dx + dy*dy + dz*dz;
    bool pred = (e < E) && (d2 < 25.0f);
    unsigned long long m = __ballot(pred ? 1 : 0);
    if ((threadIdx.x & 63) == 0) mask[e >> 6] = m;
    if (pred) {
        atomicAdd(&deg[t], 1);
        float r  = sqrtf(d2 + 1e-12f);
        float inv_r = 1.0f / r;
        int i0 = min((int)(r * ((float)TBLN / 5.0f)), TBLN - 1);
        equadE[e] = make_float4(dx * inv_r, dy * inv_r, dz * inv_r,
                                __int_as_float(i0 * 192));   // table row byte offset
        float tz = floorf(pt.w * 0.25f), tz23 = pt.w - 4.0f * tz;
        float sz = floorf(ps.w * 0.25f), sz23 = ps.w - 4.0f * sz;
        float u  = r * 0.2f;
        float u2 = u*u, u5 = u2*u2*u;
        float fcut = 1.0f - 21.0f*u5 + 35.0f*u5*u - 15.0f*u5*u2;
        float xx = r * (sz23 + tz23) * 2.134471718f;
        float phi = 0.1818f*__expf(-3.2f*xx) + 0.5099f*__expf(-0.9423f*xx)
                  + 0.2802f*__expf(-0.4029f*xx) + 0.02817f*__expf(-0.2016f*xx);
        einfoE[e] = make_int2(s, __float_as_int(tz * sz * inv_r * phi * fcut));
    }
}

// ---------------- scan pass 1 ----------------
__global__ __launch_bounds__(1024)
void k_scan1(const int* __restrict__ deg, int* __restrict__ rowptr,
             int* __restrict__ bsum, int* __restrict__ bhist,
             int* __restrict__ myslot, int N)
{
    __shared__ int wsum[16];
    __shared__ int lhist[64];
    int tid = threadIdx.x, lane = tid & 63, w = tid >> 6;
    if (tid < 64) lhist[tid] = 0;
    __syncthreads();
    int i = blockIdx.x * 1024 + tid;
    int v = (i < N) ? deg[i] : 0;
    if (i < N) myslot[i] = atomicAdd(&lhist[min(v, 63)], 1);
    int s = v;
    #pragma unroll
    for (int d = 1; d < 64; d <<= 1) {
        int u = __shfl_up(s, d);
        if (lane >= d) s += u;
    }
    if (lane == 63) wsum[w] = s;
    __syncthreads();
    if (w == 0 && lane < 16) {
        int x = wsum[lane];
        #pragma unroll
        for (int d = 1; d < 16; d <<= 1) {
            int u = __shfl_up(x, d);
            if (lane >= d) x += u;
        }
        wsum[lane] = x;
    }
    __syncthreads();
    int wave_off = (w == 0) ? 0 : wsum[w - 1];
    if (i < N) rowptr[i] = wave_off + (s - v);
    if (tid == 0) bsum[blockIdx.x] = wsum[15];
    if (tid < 64) bhist[blockIdx.x * 64 + tid] = lhist[tid];
}

// ---------------- scan pass 2 ----------------
__global__ __launch_bounds__(128)
void k_scan2(int* __restrict__ bsum, int nb, int* __restrict__ bhist,
             int* __restrict__ rowptrN)
{
    int tid = threadIdx.x;
    int lane = tid & 63;
    if (tid < 64) {
        int v = (lane < nb) ? bsum[lane] : 0;
        int s = v;
        #pragma unroll
        for (int d = 1; d < 64; d <<= 1) {
            int u = __shfl_up(s, d);
            if (lane >= d) s += u;
        }
        if (lane < nb) bsum[lane] = s - v;
        if (lane == 63) *rowptrN = s;
    } else {
        int b = lane;
        int run = 0;
        for (int blk = 0; blk < nb; ++blk) {
            int t = bhist[blk * 64 + b];
            bhist[blk * 64 + b] = run;
            run += t;
        }
        int s = run;
        #pragma unroll
        for (int d = 1; d < 64; d <<= 1) {
            int u = __shfl_up(s, d);
            if (lane >= d) s += u;
        }
        int excl = s - run;
        for (int blk = 0; blk < nb; ++blk) bhist[blk * 64 + b] += excl;
    }
}

// ---------------- scan pass 3 ----------------
__global__ __launch_bounds__(1024)
void k_scan3(const int* __restrict__ deg, int* __restrict__ rowptr,
             int* __restrict__ cursor, const int* __restrict__ bsum,
             const int* __restrict__ bhist, const int* __restrict__ myslot,
             int* __restrict__ perm, int N)
{
    int i = blockIdx.x * 1024 + threadIdx.x;
    if (i >= N) return;
    int rv = rowptr[i] + bsum[blockIdx.x];
    rowptr[i] = rv;
    cursor[i] = rv;
    int b = min(deg[i], 63);
    perm[bhist[blockIdx.x * 64 + b] + myslot[i]] = i;
}

// ---------------- place: slot copy only ----------------
__global__ __launch_bounds__(256)
void k_place(const int* __restrict__ rcv, const unsigned long long* __restrict__ mask,
             const float4* __restrict__ equadE, const int2* __restrict__ einfoE,
             int* __restrict__ cursor, float4* __restrict__ equad,
             int2* __restrict__ einfo, int E)
{
    int e = blockIdx.x * blockDim.x + threadIdx.x;
    if (e >= E) return;
    if (!((mask[e >> 6] >> (e & 63)) & 1ull)) return;
    int t = rcv[e];
    int slot = atomicAdd(&cursor[t], 1);
    equad[slot] = equadE[e];
    einfo[slot] = einfoE[e];
}

// ---------------- radial tables (both iterations) via f16 MFMA MLP ----------------
__global__ __launch_bounds__(256, 2)
void k_table(const float* __restrict__ Wr0, const float* __restrict__ Wr1,
             const float* __restrict__ Wr2, const float* __restrict__ Wr3,
             _Float16* __restrict__ table)
{
    int tb = blockIdx.x >> 5;
    const float* W0 = Wr0 + tb * NBES * HDIM;
    const float* W1 = Wr1 + tb * HDIM * HDIM;
    const float* W2 = Wr2 + tb * HDIM * HDIM;
    const float* W3 = Wr3 + tb * HDIM * 96;
    _Float16* tbl = table + (size_t)tb * TBLN * 96;

    __shared__ __align__(16) _Float16 sWt0[64*32];
    __shared__ __align__(16) _Float16 sWt1[64*64];
    __shared__ __align__(16) _Float16 sWt2[64*64];
    __shared__ __align__(16) _Float16 sWt3[96*64];
    __shared__ __align__(16) _Float16 sAct[4][64*64];

    for (int idx = threadIdx.x; idx < 64*32; idx += 256) {
        int n = idx >> 5, k = idx & 31;
        float v = (k < NBES) ? W0[k*64 + n] : 0.f;
        *(_Float16*)((char*)sWt0 + n*64 + ((k*2) ^ ((n&3)<<4))) = (_Float16)v;
    }
    for (int idx = threadIdx.x; idx < 64*64; idx += 256) {
        int k = idx >> 6, n = idx & 63;
        int byo = n*128 + ((k*2) ^ ((n&7)<<4));
        *(_Float16*)((char*)sWt1 + byo) = (_Float16)W1[idx];
        *(_Float16*)((char*)sWt2 + byo) = (_Float16)W2[idx];
    }
    for (int idx = threadIdx.x; idx < 64*96; idx += 256) {
        int k = idx / 96, n = idx - k*96;
        *(_Float16*)((char*)sWt3 + n*128 + ((k*2) ^ ((n&7)<<4))) = (_Float16)W3[idx];
    }
    __syncthreads();

    const int wid = threadIdx.x >> 6, lane = threadIdx.x & 63;
    const int l15 = lane & 15, lh = lane >> 4;
    char* actc = (char*)sAct[wid];

    half8 w1f[4], w2f[4][2], w3f[4][2], w4f[6][2];
    #pragma unroll
    for (int nt = 0; nt < 4; ++nt) {
        int nn = nt*16 + l15;
        w1f[nt] = *(half8*)((char*)sWt0 + nn*64 + ((lh*16) ^ ((nn&3)<<4)));
        #pragma unroll
        for (int ks = 0; ks < 2; ++ks) {
            w2f[nt][ks] = *(half8*)((char*)sWt1 + nn*128 + ((ks*64 + lh*16) ^ ((nn&7)<<4)));
            w3f[nt][ks] = *(half8*)((char*)sWt2 + nn*128 + ((ks*64 + lh*16) ^ ((nn&7)<<4)));
        }
    }
    #pragma unroll
    for (int nt = 0; nt < 6; ++nt) {
        int nn = nt*16 + l15;
        #pragma unroll
        for (int ks = 0; ks < 2; ++ks)
            w4f[nt][ks] = *(half8*)((char*)sWt3 + nn*128 + ((ks*64 + lh*16) ^ ((nn&7)<<4)));
    }

    int c0 = ((blockIdx.x & 31)*4 + wid)*64;
    {
        int q = c0 + lane;
        float r = (q + 0.5f) * (5.0f / (float)TBLN);
        float inv_r = 1.0f / r;
        float u  = r * 0.2f;
        float u2 = u*u, u5 = u2*u2*u;
        float fcut = 1.0f - 21.0f*u5 + 35.0f*u5*u - 15.0f*u5*u2;
        float coef = 0.632455532f * inv_r * fcut;
        half8 rv;
        #pragma unroll
        for (int j = 0; j < NBES; ++j)
            rv[j] = (_Float16)(coef * __sinf((float)(j+1) * 0.628318531f * r));
        {
            int sw = (lane & 7) << 4;
            half8 zz = {};
            *(half8*)(actc + lane*128 + ( 0 ^ sw)) = rv;
            *(half8*)(actc + lane*128 + (16 ^ sw)) = zz;
            *(half8*)(actc + lane*128 + (32 ^ sw)) = zz;
            *(half8*)(actc + lane*128 + (48 ^ sw)) = zz;
        }
        __builtin_amdgcn_sched_barrier(0);

        #pragma unroll
        for (int mt = 0; mt < 4; ++mt) {
            int rr = mt*16 + l15;
            int swz = (rr & 7) << 4;
            half8 act = *(half8*)(actc + rr*128 + ((lh*16) ^ swz));
            #pragma unroll
            for (int nt = 0; nt < 4; ++nt) {
                floatx4 z = {0.f,0.f,0.f,0.f};
                floatx4 d = __builtin_amdgcn_mfma_f32_16x16x32_f16(w1f[nt], act, z, 0,0,0);
                half4 pk;
                #pragma unroll
                for (int j = 0; j < 4; ++j) pk[j] = (_Float16)silu_f(d[j]);
                *(half4*)(actc + rr*128 + ((nt*32 + lh*8) ^ swz)) = pk;
            }
        }
        __builtin_amdgcn_sched_barrier(0);

        #pragma unroll
        for (int layer = 0; layer < 2; ++layer) {
            #pragma unroll
            for (int mt = 0; mt < 4; ++mt) {
                int rr = mt*16 + l15;
                int swz = (rr & 7) << 4;
                half8 a0 = *(half8*)(actc + rr*128 + ((      lh*16) ^ swz));
                half8 a1 = *(half8*)(actc + rr*128 + ((64 + lh*16) ^ swz));
                #pragma unroll
                for (int nt = 0; nt < 4; ++nt) {
                    floatx4 z = {0.f,0.f,0.f,0.f};
                    if (layer == 0) {
                        z = __builtin_amdgcn_mfma_f32_16x16x32_f16(w2f[nt][0], a0, z, 0,0,0);
                        z = __builtin_amdgcn_mfma_f32_16x16x32_f16(w2f[nt][1], a1, z, 0,0,0);
                    } else {
                        z = __builtin_amdgcn_mfma_f32_16x16x32_f16(w3f[nt][0], a0, z, 0,0,0);
                        z = __builtin_amdgcn_mfma_f32_16x16x32_f16(w3f[nt][1], a1, z, 0,0,0);
                    }
                    half4 pk;
                    #pragma unroll
                    for (int j = 0; j < 4; ++j) pk[j] = (_Float16)silu_f(z[j]);
                    *(half4*)(actc + rr*128 + ((nt*32 + lh*8) ^ swz)) = pk;
                }
            }
            __builtin_amdgcn_sched_barrier(0);
        }

        #pragma unroll
        for (int mt = 0; mt < 4; ++mt) {
            int rr = mt*16 + l15;
            int swz = (rr & 7) << 4;
            half8 a0 = *(half8*)(actc + rr*128 + ((      lh*16) ^ swz));
            half8 a1 = *(half8*)(actc + rr*128 + ((64 + lh*16) ^ swz));
            int e = c0 + rr;
            #pragma unroll
            for (int nt = 0; nt < 6; ++nt) {
                floatx4 z = {0.f,0.f,0.f,0.f};
                z = __builtin_amdgcn_mfma_f32_16x16x32_f16(w4f[nt][0], a0, z, 0,0,0);
                z = __builtin_amdgcn_mfma_f32_16x16x32_f16(w4f[nt][1], a1, z, 0,0,0);
                half4 pk;
                #pragma unroll
                for (int j = 0; j < 4; ++j) pk[j] = (_Float16)z[j];
                *(half4*)(tbl + (size_t)e*96 + nt*16 + lh*4) = pk;
            }
        }
    }
}

// ---------------- FUSED gather + MFMA epilogue (degree-sorted, packed edges) ----------------
template<int ITER>
__global__ __launch_bounds__(256, 5)
void k_gather_epi(const int* __restrict__ rowptr, const float4* __restrict__ equad,
                  const int2* __restrict__ einfo,
                  const _Float16* __restrict__ h1_16, const _Float16* __restrict__ hcur16,
                  const _Float16* __restrict__ table, const int* __restrict__ perm,
                  float* AO, const int* __restrict__ elem,
                  const float* __restrict__ Wprod, const float* __restrict__ Wsc,
                  const float* __restrict__ Wp, const float* __restrict__ w_ro1,
                  const float* __restrict__ W_m1, const float* __restrict__ w_m2,
                  const float* __restrict__ Wlin_next, _Float16* __restrict__ h1_next16,
                  _Float16* __restrict__ hcur_next16,
                  float* __restrict__ energy, int N)
{
    __shared__ float sWp[1024];
    __shared__ __align__(16) _Float16 sWt16[2048];
    __shared__ float sM1[(ITER == 1) ? 512 : 16];
    __shared__ float sm2[16];
    __shared__ float sro[32];
    __shared__ float sWl[(ITER == 0) ? 1024 : 16];
    __shared__ __align__(16) _Float16 sA16[32 * 296];
    __shared__ int sPerm[32];

    for (int t = threadIdx.x; t < 1024; t += 256) sWp[t] = Wprod[t];
    for (int t = threadIdx.x; t < 2048; t += 256) {
        int l = t >> 10, rem = t & 1023, d = rem >> 5, c = rem & 31;
        *(_Float16*)((char*)sWt16 + l*2048 + d*64 + ((c*2) ^ ((d&3)<<4))) =
            (_Float16)Wprod[(l + 1) * 1024 + c * 32 + d];
    }
    if (ITER == 1)
        for (int t = threadIdx.x; t < 512; t += 256) sM1[t] = W_m1[t];
    if (ITER == 0)
        for (int t = threadIdx.x; t < 1024; t += 256) sWl[t] = Wlin_next[t];
    if (threadIdx.x < 16) sm2[threadIdx.x] = w_m2[threadIdx.x];
    if (threadIdx.x < 32) {
        sro[threadIdx.x] = w_ro1[threadIdx.x];
        int idx = blockIdx.x * 32 + threadIdx.x;
        sPerm[threadIdx.x] = (idx < N) ? perm[idx] : -1;
    }
    __syncthreads();

    int lane = threadIdx.x & 63;
    int gbase = lane & 56;
    int g = threadIdx.x >> 3, j = threadIdx.x & 7, c0 = j * 4;
    int n = sPerm[g];
    bool valid = (n >= 0);

    float acc[9][4];
    #pragma unroll
    for (int m = 0; m < 9; ++m)
        #pragma unroll
        for (int q = 0; q < 4; ++q) acc[m][q] = 0.f;
    float zacc = 0.f;

    if (valid) {
        int lo = rowptr[n], hi = rowptr[n+1];

        for (int base = lo; base < hi; base += 2) {
            int k0 = base;
            bool v1 = (base + 1 < hi);
            int k1 = v1 ? (base + 1) : k0;

            float4 qd0 = equad[k0];
            float4 qd1 = equad[k1];
            int2 in0 = einfo[k0];
            int2 in1 = einfo[k1];

            const char* T00 = (const char*)table + __float_as_int(qd0.w) + c0 * 2;
            const char* T10 = (const char*)table + __float_as_int(qd1.w) + c0 * 2;
            half4 e0a0 = *(const half4*)(T00);
            half4 e0a1 = *(const half4*)(T00 + 64);
            half4 e0a2 = *(const half4*)(T00 + 128);
            half4 e1a0 = *(const half4*)(T10);
            half4 e1a1 = *(const half4*)(T10 + 64);
            half4 e1a2 = *(const half4*)(T10 + 128);

            half4 hv0 = *(const half4*)(h1_16 + (size_t)in0.x * Cdim + c0);
            half4 hv1 = *(const half4*)(h1_16 + (size_t)in1.x * Cdim + c0);

            float vf1 = v1 ? 1.0f : 0.0f;

            if (ITER == 0) {
                zacc += __int_as_float(in0.y);
                zacc += vf1 * __int_as_float(in1.y);
            }

            // ---- edge 0 ----
            {
                float ux = qd0.x, uy = qd0.y, uz = qd0.z;
                const float s3 = 1.73205081f, s5 = 2.23606798f, s15 = 3.87298335f;
                float sh1 = s3 * ux, sh2 = s3 * uy, sh3 = s3 * uz;
                float sh4 = s15 * ux * uy, sh5 = s15 * uy * uz;
                float sh6 = 0.5f * s5 * (3.0f * uz * uz - 1.0f);
                float sh7 = s15 * ux * uz;
                float sh8 = 0.5f * s15 * (ux * ux - uy * uy);

                #pragma unroll
                for (int q = 0; q < 4; ++q) {
                    float hb = (float)hv0[q];
                    float m0 = hb * (float)e0a0[q];
                    float m1 = hb * (float)e0a1[q];
                    float m2 = hb * (float)e0a2[q];
                    acc[0][q] += m0;
                    acc[1][q] += sh1 * m1;
                    acc[2][q] += sh2 * m1;
                    acc[3][q] += sh3 * m1;
                    acc[4][q] += sh4 * m2;
                    acc[5][q] += sh5 * m2;
                    acc[6][q] += sh6 * m2;
                    acc[7][q] += sh7 * m2;
                    acc[8][q] += sh8 * m2;
                }
            }
            // ---- edge 1 (weight vf1) ----
            {
                float ux = qd1.x, uy = qd1.y, uz = qd1.z;
                const float s3 = 1.73205081f, s5 = 2.23606798f, s15 = 3.87298335f;
                float sh1 = s3 * ux, sh2 = s3 * uy, sh3 = s3 * uz;
                float sh4 = s15 * ux * uy, sh5 = s15 * uy * uz;
                float sh6 = 0.5f * s5 * (3.0f * uz * uz - 1.0f);
                float sh7 = s15 * ux * uz;
                float sh8 = 0.5f * s15 * (ux * ux - uy * uy);

                #pragma unroll
                for (int q = 0; q < 4; ++q) {
                    float hb = (float)hv1[q] * vf1;
                    float m0 = hb * (float)e1a0[q];
                    float m1 = hb * (float)e1a1[q];
                    float m2 = hb * (float)e1a2[q];
                    acc[0][q] += m0;
                    acc[1][q] += sh1 * m1;
                    acc[2][q] += sh2 * m1;
                    acc[3][q] += sh3 * m1;
                    acc[4][q] += sh4 * m2;
                    acc[5][q] += sh5 * m2;
                    acc[6][q] += sh6 * m2;
                    acc[7][q] += sh7 * m2;
                    acc[8][q] += sh8 * m2;
                }
            }
        }

        #pragma unroll
        for (int m = 1; m <= 8; ++m) {
            half4 pk;
            #pragma unroll
            for (int q = 0; q < 4; ++q) pk[q] = (_Float16)(acc[m][q] * 0.0625f);
            *(half4*)((char*)sA16 + g * 592 + m * 64 + j * 8) = pk;
        }
    }
    __syncthreads();

    // ---- MFMA phase: out[m] = (A_m/16) @ Wprod[L[m]], m=1..8 ----
    {
        int w = threadIdx.x >> 6;
        int l15 = lane & 15, lh = lane >> 4;
        int nhalf = (w >> 1) * 16;
        int mbase = (w & 1) * 4 + 1;
        int node = sPerm[nhalf + l15];
        const int outslot = (ITER == 0) ? 0 : 288;

        half8 af[2][2];
        #pragma unroll
        for (int l = 0; l < 2; ++l)
            #pragma unroll
            for (int nt = 0; nt < 2; ++nt) {
                int row = nt * 16 + l15;
                af[l][nt] = *(half8*)((char*)sWt16 + l*2048 + row*64 +
                                      ((lh*16) ^ ((row&3)<<4)));
            }
        #pragma unroll
        for (int mi = 0; mi < 4; ++mi) {
            int m = mbase + mi;
            int l = (m <= 3) ? 0 : 1;
            half8 bf = *(half8*)((char*)sA16 + (nhalf + l15) * 592 + m * 64 + lh * 16);
            #pragma unroll
            for (int nt = 0; nt < 2; ++nt) {
                floatx4 z = {0.f, 0.f, 0.f, 0.f};
                z = __builtin_amdgcn_mfma_f32_16x16x32_f16(af[l][nt], bf, z, 0, 0, 0);
                if (node >= 0)
                    *(floatx4*)(AO + (size_t)node * 576 + outslot + m * 32 +
                                nt * 16 + lh * 4) = z;
            }
        }
    }

    // ---- hs / scalar channel ----
    if (valid) {
        int el = elem[n];
        half4 hq4 = *(const half4*)(hcur16 + (size_t)n * Cdim + c0);
        float4 hown = make_float4((float)hq4[0], (float)hq4[1],
                                  (float)hq4[2], (float)hq4[3]);
        float4 A0own = make_float4(acc[0][0]*0.0625f, acc[0][1]*0.0625f,
                                   acc[0][2]*0.0625f, acc[0][3]*0.0625f);
        const float* Ws = Wsc + (size_t)el * 1024;
        float hs[4] = {0.f, 0.f, 0.f, 0.f};

        #pragma unroll
        for (int j2 = 0; j2 < 8; ++j2) {
            int src = gbase + j2;
            float4 a4 = shfl4(A0own, src);
            float4 h4 = shfl4(hown, src);
            float aq[4] = {a4.x, a4.y, a4.z, a4.w};
            float hq[4] = {h4.x, h4.y, h4.z, h4.w};
            #pragma unroll
            for (int q = 0; q < 4; ++q) {
                int c = j2 * 4 + q;
                float4 wp = *(const float4*)&sWp[c * 32 + c0];
                float4 wv = *(const float4*)(Ws + c * 32 + c0);
                hs[0] += aq[q] * wp.x + hq[q] * wv.x;
                hs[1] += aq[q] * wp.y + hq[q] * wv.y;
                hs[2] += aq[q] * wp.z + hq[q] * wv.z;
                hs[3] += aq[q] * wp.w + hq[q] * wv.w;
            }
        }
        {
            const float* wpb = Wp + el * 32;
            float4 p1 = *(const float4*)(wpb + c0);
            float4 p2 = *(const float4*)(wpb + 320 + c0);
            float4 p3 = *(const float4*)(wpb + 640 + c0);
            float p1a[4] = {p1.x, p1.y, p1.z, p1.w};
            float p2a[4] = {p2.x, p2.y, p2.z, p2.w};
            float p3a[4] = {p3.x, p3.y, p3.z, p3.w};
            #pragma unroll
            for (int d = 0; d < 4; ++d) {
                float A = acc[0][d] * 0.0625f, A2 = A * A;
                hs[d] += p1a[d] * A + p2a[d] * A2 + p3a[d] * (A2 * A);
            }
        }

        float eadd;
        if (ITER == 0) {
            float a = hs[0]*sro[c0] + hs[1]*sro[c0+1] + hs[2]*sro[c0+2] + hs[3]*sro[c0+3];
            a += __shfl_xor(a, 1); a += __shfl_xor(a, 2); a += __shfl_xor(a, 4);
            eadd = a + 7.1998f * zacc;
        } else {
            float tj[16];
            #pragma unroll
            for (int q = 0; q < 16; ++q) {
                float tv = 0.f;
                #pragma unroll
                for (int d = 0; d < 4; ++d) tv += hs[d] * sM1[(c0 + d) * 16 + q];
                tv += __shfl_xor(tv, 1); tv += __shfl_xor(tv, 2); tv += __shfl_xor(tv, 4);
                tj[q] = tv;
            }
            float a = 0.f;
            #pragma unroll
            for (int q = 0; q < 16; ++q) a += silu_f(tj[q]) * sm2[q];
            eadd = a;
        }
        if (j == 0) energy[n] += eadd;

        const int outslot = (ITER == 0) ? 0 : 288;
        *(float4*)(AO + (size_t)n * 576 + outslot + c0) = make_float4(hs[0], hs[1], hs[2], hs[3]);

        if (ITER == 0) {
            half4 ph;
            #pragma unroll
            for (int q = 0; q < 4; ++q) ph[q] = (_Float16)hs[q];
            *(half4*)(hcur_next16 + (size_t)n * Cdim + c0) = ph;

            float4 hsv = make_float4(hs[0], hs[1], hs[2], hs[3]);
            float o[4] = {0.f, 0.f, 0.f, 0.f};
            #pragma unroll
            for (int j2 = 0; j2 < 8; ++j2) {
                float4 h4 = shfl4(hsv, gbase + j2);
                float hq[4] = {h4.x, h4.y, h4.z, h4.w};
                #pragma unroll
                for (int q = 0; q < 4; ++q) {
                    float4 wv = *(const float4*)&sWl[(j2 * 4 + q) * 32 + c0];
                    o[0] += hq[q] * wv.x; o[1] += hq[q] * wv.y;
                    o[2] += hq[q] * wv.z; o[3] += hq[q] * wv.w;
                }
            }
            half4 p1;
            #pragma unroll
            for (int q = 0; q < 4; ++q) p1[q] = (_Float16)o[q];
            *(half4*)(h1_next16 + (size_t)n * Cdim + c0) = p1;
        }
    }
}

extern "C" void kernel_launch(void* const* d_in, const int* in_sizes, int n_in,
                              void* d_out, int out_size, void* d_ws, size_t ws_size,
                              hipStream_t stream)
{
    const float* attrs   = (const float*)d_in[0];
    const float* pos     = (const float*)d_in[1];
    const int*   snd     = (const int*)d_in[2];
    const int*   rcv     = (const int*)d_in[3];
    const float* W_embed = (const float*)d_in[4];
    const float* atomE   = (const float*)d_in[5];
    const float* Wr0     = (const float*)d_in[6];
    const float* Wr1     = (const float*)d_in[7];
    const float* Wr2     = (const float*)d_in[8];
    const float* Wr3     = (const float*)d_in[9];
    const float* Wlin    = (const float*)d_in[10];
    const float* Wsc     = (const float*)d_in[11];
    const float* Wprod   = (const float*)d_in[12];
    const float* Wp      = (const float*)d_in[13];
    const float* w_ro1   = (const float*)d_in[14];
    const float* W_m1    = (const float*)d_in[15];
    const float* w_m2    = (const float*)d_in[16];

    const int N = in_sizes[1] / 3;
    const int E = in_sizes[2];

    float* energy = (float*)d_out;
    float* feats  = (float*)d_out + N;

    char* ws = (char*)d_ws;
    size_t off = 0;
    auto alloc = [&](size_t bytes) { void* p = ws + off; off = (off + bytes + 255) & ~(size_t)255; return p; };
    int*  deg    = (int*)alloc((size_t)N * 4);
    int*  cursor = (int*)alloc((size_t)N * 4);
    int*  rowptr = (int*)alloc((size_t)(N + 1) * 4);
    unsigned long long* mask = (unsigned long long*)alloc((size_t)((E + 63) / 64) * 8);
    float4* equad  = (float4*)alloc((size_t)E * 16);
    int2*   einfo  = (int2*)alloc((size_t)E * 8);
    float4* equadE = (float4*)alloc((size_t)E * 16);
    int2*   einfoE = (int2*)alloc((size_t)E * 8);
    int*  elem   = (int*)alloc((size_t)N * 4);
    float4* pos4 = (float4*)alloc((size_t)N * 16);
    _Float16* h16cur = (_Float16*)alloc((size_t)N * Cdim * 2);
    _Float16* h16b   = (_Float16*)alloc((size_t)N * Cdim * 2);
    _Float16* h1a16  = (_Float16*)alloc((size_t)N * Cdim * 2);
    _Float16* h1b16  = (_Float16*)alloc((size_t)N * Cdim * 2);
    _Float16* table = (_Float16*)alloc((size_t)2 * TBLN * 96 * 2);
    int* bsum   = (int*)alloc(64 * 4);
    int* bhist  = (int*)alloc(64 * 64 * 4);
    int* myslot = (int*)alloc((size_t)N * 4);
    int* perm   = (int*)alloc((size_t)N * 4);

    const int NB1024 = (N + 1023) / 1024;

    k_node_init<<<(N + 255)/256, 256, 0, stream>>>(attrs, pos, W_embed, atomE, Wlin, elem,
                                                   energy, deg, pos4, h16cur, h1a16, N);
    k_filter<<<(E + 255)/256, 256, 0, stream>>>(pos4, snd, rcv, mask, deg, equadE, einfoE, E);
    k_scan1<<<NB1024, 1024, 0, stream>>>(deg, rowptr, bsum, bhist, myslot, N);
    k_scan2<<<1, 128, 0, stream>>>(bsum, NB1024, bhist, rowptr + N);
    k_scan3<<<NB1024, 1024, 0, stream>>>(deg, rowptr, cursor, bsum, bhist, myslot, perm, N);
    k_place<<<(E + 255)/256, 256, 0, stream>>>(rcv, mask, equadE, einfoE, cursor,
                                               equad, einfo, E);
    k_table<<<64, 256, 0, stream>>>(Wr0, Wr1, Wr2, Wr3, table);

    const int NBLK = (N + 31) / 32;

    // ---- iteration 0 ----
    k_gather_epi<0><<<NBLK, 256, 0, stream>>>(rowptr, equad, einfo, h1a16, h16cur, table,
        perm, feats, elem, Wprod, Wsc, Wp, w_ro1, W_m1, w_m2,
        Wlin + 1024, h1b16, h16b, energy, N);

    // ---- iteration 1 ----
    k_gather_epi<1><<<NBLK, 256, 0, stream>>>(rowptr, equad, einfo, h1b16, h16b,
        table + (size_t)TBLN * 96,
        perm, feats, elem, Wprod + 3072, Wsc + 10240, Wp + 960, w_ro1, W_m1, w_m2,
        Wlin, h1b16, h16b, energy, N);
}